// Round 3
// baseline (308.996 us; speedup 1.0000x reference)
//
#include <hip/hip_runtime.h>
#include <hip/hip_cooperative_groups.h>
#include <math.h>

namespace cg = cooperative_groups;

// Problem: B=8, V=8, N=1000, D=256, H=8, KS=32
// ws float offsets
#define OFF_MW      0          // 768*8 = 6144
#define OFF_QUERY   6144       // 16384 -> 22528
#define OFF_LOGMASK 22528      // 64000 -> 86528
#define OFF_CSUM    86528      // 64    -> 86592
#define OFF_HSTAT   86592      // 16384 -> 102976
#define OFF_S8      102976     // 4096  -> 107072
#define OFF_FQ      107072     // 16384 -> 123456
#define OFF_LQM     123456     // 512   -> 123968
#define OFF_RED     123968     // 8 x u64 packed argmax (16 floats) + 8 expsum
#define N_ZERO_STATS 20544     // csum + hstat + s8
#define N_ZERO_RED   24

__device__ inline float waveSum(float v){
  #pragma unroll
  for (int o = 32; o > 0; o >>= 1) v += __shfl_down(v, o, 64);
  return v;
}
__device__ inline unsigned long long waveMaxU(unsigned long long v){
  #pragma unroll
  for (int o = 32; o > 0; o >>= 1) {
    unsigned long long w = __shfl_down(v, o, 64);
    v = (w > v) ? w : v;
  }
  return v;
}
// monotone float->uint encoding (order-preserving incl. -inf)
__device__ inline unsigned encF(float f){
  unsigned u = __float_as_uint(f);
  return (u & 0x80000000u) ? ~u : (u | 0x80000000u);
}
__device__ inline float decF(unsigned u){
  return (u & 0x80000000u) ? __uint_as_float(u & 0x7fffffffu)
                           : __uint_as_float(~u);
}

// phase = -1: run all phases with grid.sync() (cooperative launch).
// phase = 0..4: run only that phase (fallback, separate launches).
__global__ __launch_bounds__(256) void fused_decoder(
    const float* __restrict__ node_dyn, const float* __restrict__ gVs,
    const float* __restrict__ gKs, const float* __restrict__ lKs,
    const void* __restrict__ maskp, const float* __restrict__ fixedc,
    const float* __restrict__ prev, const float* __restrict__ veh,
    const float* __restrict__ pcs, const float* __restrict__ pns1,
    const float* __restrict__ pns2, const float* __restrict__ po,
    float* __restrict__ W, float* __restrict__ out, int phase)
{
  const int blk = blockIdx.x, tid = threadIdx.x;
  const bool coop = (phase < 0);
  cg::grid_group grid = cg::this_grid();

  float* mw      = W + OFF_MW;
  float* queryp  = W + OFF_QUERY;
  float* logmask = W + OFF_LOGMASK;
  float* csum    = W + OFF_CSUM;
  float* hstat   = W + OFF_HSTAT;
  float* s8      = W + OFF_S8;
  float* fqp     = W + OFF_FQ;
  float* lqm     = W + OFF_LQM;
  unsigned long long* packed = (unsigned long long*)(W + OFF_RED);
  float* expsum  = W + OFF_RED + 16;

  __shared__ __align__(16) float p[2000];
  __shared__ __align__(16) float gq[256];
  __shared__ float qmk[64];
  __shared__ float red4[4];
  __shared__ float mred[28];
  __shared__ __align__(16) float cvs[264];
  __shared__ __align__(16) float cl[256];
  __shared__ float fql[256];
  __shared__ float part[256];
  __shared__ unsigned long long rP[4];
  __shared__ int bytemode;

  // ---------------- phase 0: Mw, query, logmask, zero stats ----------------
  if (coop || phase == 0) {
    // Mw rows 3 per block: Mw[i][f<7] = pns1[i,f] + sum_j pns2[i,j]*pns1[j,f]
    for (int r = 0; r < 3; r++) {
      int i = blk * 3 + r;
      const float* row = pns2 + (size_t)i * 769;
      float acc[7] = {0.f,0.f,0.f,0.f,0.f,0.f,0.f};
      #pragma unroll
      for (int t = 0; t < 3; t++) {
        int j = tid + 256 * t;
        float rv = row[j];
        const float* wv = pns1 + j * 7;
        #pragma unroll
        for (int f = 0; f < 7; f++) acc[f] += rv * wv[f];
      }
      #pragma unroll
      for (int f = 0; f < 7; f++) {
        float v = waveSum(acc[f]);
        if ((tid & 63) == 0) mred[(tid >> 6) * 7 + f] = v;
      }
      __syncthreads();
      if (tid < 7) {
        float s = mred[tid] + mred[7 + tid] + mred[14 + tid] + mred[21 + tid];
        mw[i * 8 + tid] = pns1[i * 7 + tid] + s;
      } else if (tid == 7) {
        mw[i * 8 + 7] = row[768];
      }
      __syncthreads();
    }
    // query (blocks 0..63): query[bv][d] = fixed[b][d] + cvs . pcs[d]
    if (blk < 64) {
      int bv = blk;
      if (tid < 256) cvs[tid] = prev[(size_t)bv * 256 + tid];
      if (tid < 8)   cvs[256 + tid] = veh[bv * 8 + tid];
      __syncthreads();
      int b = bv >> 3;
      float a = fixedc[b * 256 + tid];
      const float4* c4 = (const float4*)cvs;
      const float4* w4 = (const float4*)(pcs + (size_t)tid * 264);
      #pragma unroll 4
      for (int k = 0; k < 66; k++) {
        float4 cc = c4[k], wv = w4[k];
        a += cc.x*wv.x + cc.y*wv.y + cc.z*wv.z + cc.w*wv.w;
      }
      queryp[(size_t)bv * 256 + tid] = a;
    }
    // logmask: 250 elems per block, mask dtype auto-detect
    if (tid == 0) {
      int bm = 0;
      const unsigned char* mb = (const unsigned char*)maskp;
      for (int idx = 1; idx < 256; idx++)
        if ((idx & 3) != 0 && mb[idx] != 0) { bm = 1; break; }
      bytemode = bm;
    }
    __syncthreads();
    {
      int g = blk * 250 + tid;
      if (tid < 250) {
        bool on = bytemode ? (((const unsigned char*)maskp)[g] != 0)
                           : (((const int*)maskp)[g] != 0);
        logmask[g] = on ? 0.0f : -INFINITY;
      }
    }
    // zero atomic destinations: stats (csum/hstat/s8) + RED
    {
      int g = blk * 256 + tid;
      if (g < N_ZERO_STATS) csum[g] = 0.f;   // csum is base of contiguous region
      else if (g < N_ZERO_STATS + N_ZERO_RED) W[OFF_RED + (g - N_ZERO_STATS)] = 0.f;
    }
  }
  if (coop) grid.sync();

  // ---------------- phase 1: attention stats ----------------
  if (coop || phase == 1) {
    int h = blk >> 5, b1 = (blk >> 2) & 7, q = blk & 3;
    int hb = h * 8 + b1, n0 = q * 250;
    gq[tid] = queryp[(size_t)(b1 * 8 + (tid >> 5)) * 256 + h * 32 + (tid & 31)];
    __syncthreads();
    if (tid < 64) {
      int v = tid >> 3, f = tid & 7;
      float a = 0.f;
      for (int k = 0; k < 32; k++)
        a += gq[v * 32 + k] * mw[(256 + h * 32 + k) * 8 + f];
      qmk[tid] = a;
    }
    __syncthreads();
    float tsum = 0.f;
    for (int e = tid; e < 2000; e += 256) {
      int v = e / 250; int i = e - v * 250; int n = n0 + i;
      const float4* nd4 = (const float4*)(node_dyn + ((size_t)(b1*8+v)*1000 + n) * 8);
      float4 ndA = nd4[0], ndB = nd4[1];
      const float4* gk4 = (const float4*)(gKs + ((size_t)hb * 1000 + n) * 32);
      const float4* gq4 = (const float4*)(gq + v * 32);
      float s = 0.f;
      #pragma unroll
      for (int k4 = 0; k4 < 8; k4++) {
        float4 g = gk4[k4], qq = gq4[k4];
        s += g.x*qq.x + g.y*qq.y + g.z*qq.z + g.w*qq.w;
      }
      const float* qm = qmk + v * 8;
      float dyn = ndA.x*qm[0] + ndA.y*qm[1] + ndA.z*qm[2] + ndA.w*qm[3]
                + ndB.x*qm[4] + ndB.y*qm[5] + ndB.z*qm[6] + ndB.w*qm[7];
      float cc = (s + dyn) * 0.17677669529663687f + logmask[(b1*8+v)*1000 + n];
      float pv = __expf(cc);   // no max-subtraction: |cc| small, softmax invariant
      p[e] = pv;
      tsum += pv;
    }
    tsum = waveSum(tsum);
    if ((tid & 63) == 0) red4[tid >> 6] = tsum;
    __syncthreads();
    if (tid == 0) atomicAdd(csum + hb, red4[0]+red4[1]+red4[2]+red4[3]);
    // hstat[hb][v][k] += sum_i p * gVs
    {
      int v = tid >> 5, k = tid & 31;
      const float* gv = gVs + ((size_t)hb * 1000 + n0) * 32 + k;
      const float* pr = p + v * 250;
      float a = 0.f;
      #pragma unroll 5
      for (int i = 0; i < 250; i++) a += pr[i] * gv[(size_t)i * 32];
      atomicAdd(hstat + hb * 256 + tid, a);
    }
    // s8[hb][v][f] += sum_i p * nd8
    if (tid < 64) {
      int v = tid >> 3, f = tid & 7;
      const float* ndp = node_dyn + ((size_t)(b1*8+v)*1000 + n0) * 8 + f;
      const float* pr = p + v * 250;
      float a = 0.f;
      #pragma unroll 5
      for (int i = 0; i < 250; i++) a += pr[i] * ndp[i * 8];
      atomicAdd(s8 + hb * 64 + tid, a);
    }
  }
  if (coop) grid.sync();

  // ---------------- phase 2: conc assembly + final_Q + lqM ----------------
  if ((coop && blk < 64) || phase == 2) {
    int bv = coop ? blk : blk;   // fallback launches grid=64
    int b = bv >> 3, v = bv & 7;
    {
      int h2 = tid >> 5, k2 = tid & 31, hb2 = h2 * 8 + b;
      float dyn = 0.f;
      const float* s8p = s8 + hb2 * 64 + v * 8;
      const float* mwp = mw + (h2 * 32 + k2) * 8;
      #pragma unroll
      for (int f = 0; f < 8; f++) dyn += s8p[f] * mwp[f];
      cl[tid] = (hstat[hb2 * 256 + v * 32 + k2] + dyn) / csum[hb2];
    }
    __syncthreads();
    float a = 0.f;
    const float4* c4 = (const float4*)cl;
    const float4* w4 = (const float4*)(po + (size_t)tid * 256);
    #pragma unroll 4
    for (int e = 0; e < 64; e++) {
      float4 cc = c4[e], wv = w4[e];
      a += cc.x*wv.x + cc.y*wv.y + cc.z*wv.z + cc.w*wv.w;
    }
    fql[tid] = a;
    fqp[(size_t)bv * 256 + tid] = a;
    __syncthreads();
    {
      int c2 = tid >> 3, f = tid & 7;
      float s = 0.f;
      for (int d = c2 * 8; d < c2 * 8 + 8; d++) s += fql[d] * mw[(512 + d) * 8 + f];
      part[tid] = s;
    }
    __syncthreads();
    if (tid < 8) {
      float s = 0.f;
      for (int c2 = 0; c2 < 32; c2++) s += part[c2 * 8 + tid];
      lqm[bv * 8 + tid] = s;
    }
  }
  if (coop) grid.sync();

  // ---------------- phase 3: logits + per-b expsum/argmax (no logits store) --
  if (coop || phase == 3) {
    int b = blk >> 5, slice = blk & 31;
    int nn = tid >> 3, v = tid & 7;
    int n = slice * 32 + nn;
    bool valid = (n < 1000);
    int n_c = valid ? n : 999;
    const float4* A  = (const float4*)(fqp + (size_t)(b * 8 + v) * 256);
    const float4* Bk = (const float4*)(lKs + ((size_t)(b * 1000 + n_c)) * 256);
    float s = 0.f;
    #pragma unroll 8
    for (int d4 = 0; d4 < 64; d4++) {
      float4 x = A[d4], y = Bk[d4];
      s += x.x*y.x + x.y*y.y + x.z*y.z + x.w*y.w;
    }
    const float4* nd4 = (const float4*)(node_dyn + ((size_t)((b*8+v)*1000 + n_c)) * 8);
    float4 na = nd4[0], nb = nd4[1];
    const float* qm = lqm + (b * 8 + v) * 8;
    float dyn = na.x*qm[0] + na.y*qm[1] + na.z*qm[2] + na.w*qm[3]
              + nb.x*qm[4] + nb.y*qm[5] + nb.z*qm[6] + nb.w*qm[7];
    float z = (s + dyn) * 0.0625f;
    float L = tanhf(z) * 10.0f + logmask[(b * 8 + v) * 1000 + n_c];
    if (!valid) L = -INFINITY;
    float ex = __expf(L);                     // exp(-inf) = 0
    unsigned idx = (unsigned)(v * 1000 + n_c);
    unsigned long long pk = ((unsigned long long)encF(L) << 32) | (unsigned)(~idx);
    float sEx = waveSum(ex);
    unsigned long long mP = waveMaxU(pk);
    if ((tid & 63) == 0) { red4[tid >> 6] = sEx; rP[tid >> 6] = mP; }
    __syncthreads();
    if (tid == 0) {
      float S = red4[0] + red4[1] + red4[2] + red4[3];
      unsigned long long P = rP[0];
      #pragma unroll
      for (int i = 1; i < 4; i++) P = (rP[i] > P) ? rP[i] : P;
      atomicAdd(expsum + b, S);
      atomicMax(packed + b, P);
    }
  }
  if (coop) grid.sync();

  // ---------------- phase 4: outputs ----------------
  if ((coop && blk == 0) || phase == 4) {
    if (blk == 0 && tid < 64) {
      float c = 0.f;
      if (tid < 8) {
        unsigned long long pk = packed[tid];
        float best = decF((unsigned)(pk >> 32));
        unsigned idx = ~(unsigned)(pk & 0xffffffffu);
        float S = expsum[tid];
        float logprob = best - logf(S);
        float prob = __expf(logprob);
        out[tid]      = (float)(idx / 1000);
        out[8 + tid]  = (float)(idx % 1000);
        out[16 + tid] = logprob;
        c = prob * logprob;
      }
      c = waveSum(c);
      if (tid == 0) out[24] = -c;
    }
  }
}

extern "C" void kernel_launch(void* const* d_in, const int* in_sizes, int n_in,
                              void* d_out, int out_size, void* d_ws, size_t ws_size,
                              hipStream_t stream) {
  const float* fixedc   = (const float*)d_in[1];
  const float* prev     = (const float*)d_in[2];
  const float* node_dyn = (const float*)d_in[3];
  const float* veh      = (const float*)d_in[4];
  const float* gVs      = (const float*)d_in[5];
  const float* gKs      = (const float*)d_in[6];
  const float* lKs      = (const float*)d_in[7];
  const void*  mask     = d_in[8];
  const float* pcs      = (const float*)d_in[9];
  const float* pns1     = (const float*)d_in[10];
  const float* pns2     = (const float*)d_in[11];
  const float* po       = (const float*)d_in[12];
  float* W   = (float*)d_ws;
  float* out = (float*)d_out;

  int phase = -1;
  void* args[] = {
    (void*)&node_dyn, (void*)&gVs, (void*)&gKs, (void*)&lKs, (void*)&mask,
    (void*)&fixedc, (void*)&prev, (void*)&veh, (void*)&pcs, (void*)&pns1,
    (void*)&pns2, (void*)&po, (void*)&W, (void*)&out, (void*)&phase
  };
  hipError_t err = hipLaunchCooperativeKernel((const void*)fused_decoder,
                                              dim3(256), dim3(256), args, 0, stream);
  if (err != hipSuccess) {
    // fallback: 5 stream-ordered phase launches
    fused_decoder<<<256, 256, 0, stream>>>(node_dyn, gVs, gKs, lKs, mask, fixedc,
        prev, veh, pcs, pns1, pns2, po, W, out, 0);
    fused_decoder<<<256, 256, 0, stream>>>(node_dyn, gVs, gKs, lKs, mask, fixedc,
        prev, veh, pcs, pns1, pns2, po, W, out, 1);
    fused_decoder<<<64, 256, 0, stream>>>(node_dyn, gVs, gKs, lKs, mask, fixedc,
        prev, veh, pcs, pns1, pns2, po, W, out, 2);
    fused_decoder<<<256, 256, 0, stream>>>(node_dyn, gVs, gKs, lKs, mask, fixedc,
        prev, veh, pcs, pns1, pns2, po, W, out, 3);
    fused_decoder<<<1, 256, 0, stream>>>(node_dyn, gVs, gKs, lKs, mask, fixedc,
        prev, veh, pcs, pns1, pns2, po, W, out, 4);
  }
}

// Round 4
// 176.729 us; speedup vs baseline: 1.7484x; 1.7484x over previous
//
#include <hip/hip_runtime.h>
#include <math.h>

// Problem: B=8, V=8, N=1000, D=256, H=8, KS=32
// ws float offsets
#define OFF_MW      0          // 768*8 = 6144
#define OFF_QUERY   6144       // 16384 -> 22528
#define OFF_LOGMASK 22528      // 64000 -> 86528
#define OFF_CSUM    86528      // 64       (atomic region base)
#define OFF_HSTAT   86592      // 16384
#define OFF_S8      102976     // 4096
#define OFF_PACKED  107072     // 8 u64 = 16 floats
#define OFF_EXPSUM  107088     // 8
#define OFF_DONE    107096     // 1
#define OFF_FQ      107104     // 16384
#define OFF_LQM     123488     // 512 -> ends 123,? (well under ws)
#define N_ZERO      20569      // csum..done contiguous zero region

__device__ inline float waveSum(float v){
  #pragma unroll
  for (int o = 32; o > 0; o >>= 1) v += __shfl_down(v, o, 64);
  return v;
}
__device__ inline unsigned long long waveMaxU(unsigned long long v){
  #pragma unroll
  for (int o = 32; o > 0; o >>= 1) {
    unsigned long long w = __shfl_down(v, o, 64);
    v = (w > v) ? w : v;
  }
  return v;
}
// monotone float->uint encoding (order-preserving incl. -inf)
__device__ inline unsigned encF(float f){
  unsigned u = __float_as_uint(f);
  return (u & 0x80000000u) ? ~u : (u | 0x80000000u);
}
__device__ inline float decF(unsigned u){
  return (u & 0x80000000u) ? __uint_as_float(u & 0x7fffffffu)
                           : __uint_as_float(~u);
}

// K_prep: [0,768) Mw rows; [768,832) query; [832,1082) logmask.
// Blocks [0,84) additionally zero the atomic-destination region.
__global__ __launch_bounds__(256) void k_prep(
    const float* __restrict__ pns1, const float* __restrict__ pns2,
    const float* __restrict__ prev, const float* __restrict__ veh,
    const float* __restrict__ fixedc, const float* __restrict__ pcs,
    const void* __restrict__ maskp, float* __restrict__ W)
{
  int blk = blockIdx.x, tid = threadIdx.x;
  float* mw      = W + OFF_MW;
  float* queryp  = W + OFF_QUERY;
  float* logmask = W + OFF_LOGMASK;

  if (blk < 84) {
    int g = blk * 256 + tid;
    if (g < N_ZERO) (W + OFF_CSUM)[g] = 0.f;
  }

  if (blk < 768) {
    // Mw[i][f<7] = pns1[i,f] + sum_j pns2[i,j]*pns1[j,f]; Mw[i][7]=pns2[i,768]
    int i = blk;
    __shared__ float red[28];
    const float* row = pns2 + (size_t)i * 769;
    float acc[7] = {0.f,0.f,0.f,0.f,0.f,0.f,0.f};
    #pragma unroll
    for (int t = 0; t < 3; t++) {
      int j = tid + 256 * t;
      float r = row[j];
      const float* w = pns1 + j * 7;
      #pragma unroll
      for (int f = 0; f < 7; f++) acc[f] += r * w[f];
    }
    #pragma unroll
    for (int f = 0; f < 7; f++) {
      float v = waveSum(acc[f]);
      if ((tid & 63) == 0) red[(tid >> 6) * 7 + f] = v;
    }
    __syncthreads();
    if (tid < 7) {
      float s = red[tid] + red[7 + tid] + red[14 + tid] + red[21 + tid];
      mw[i * 8 + tid] = pns1[i * 7 + tid] + s;
    } else if (tid == 7) {
      mw[i * 8 + 7] = row[768];
    }
  } else if (blk < 832) {
    int bv = blk - 768;
    __shared__ __align__(16) float cvs[264];
    cvs[tid] = prev[(size_t)bv * 256 + tid];
    if (tid < 8) cvs[256 + tid] = veh[bv * 8 + tid];
    __syncthreads();
    int b = bv >> 3;
    float a = fixedc[b * 256 + tid];
    const float4* c4 = (const float4*)cvs;
    const float4* w4 = (const float4*)(pcs + (size_t)tid * 264);
    #pragma unroll 4
    for (int k = 0; k < 66; k++) {
      float4 cv = c4[k], wv = w4[k];
      a += cv.x*wv.x + cv.y*wv.y + cv.z*wv.z + cv.w*wv.w;
    }
    queryp[(size_t)bv * 256 + tid] = a;
  } else {
    // logmask, mask dtype auto-detect (bool-u8 vs int32)
    __shared__ int bytemode;
    if (tid == 0) {
      int bm = 0;
      const unsigned char* mb = (const unsigned char*)maskp;
      for (int idx = 1; idx < 256; idx++)
        if ((idx & 3) != 0 && mb[idx] != 0) { bm = 1; break; }
      bytemode = bm;
    }
    __syncthreads();
    int g = (blk - 832) * 256 + tid;
    if (g < 64000) {
      bool on = bytemode ? (((const unsigned char*)maskp)[g] != 0)
                         : (((const int*)maskp)[g] != 0);
      logmask[g] = on ? 0.0f : -INFINITY;
    }
  }
}

// K_attn: grid 512 = (h, c, b), 125 nodes x 8 v per block.
// compat -> exp (no max-sub; softmax shift-invariant) -> atomics.
__global__ __launch_bounds__(256) void k_attn(
    const float* __restrict__ node_dyn, const float* __restrict__ gVs,
    const float* __restrict__ gKs, float* __restrict__ W)
{
  int blk = blockIdx.x;
  int b = blk & 7, c = (blk >> 3) & 7, h = blk >> 6;
  int hb = h * 8 + b, n0 = c * 125;
  int tid = threadIdx.x;
  const float* mw      = W + OFF_MW;
  const float* queryp  = W + OFF_QUERY;
  const float* logmask = W + OFF_LOGMASK;
  float* csum  = W + OFF_CSUM;
  float* hstat = W + OFF_HSTAT;
  float* s8    = W + OFF_S8;

  __shared__ __align__(16) float p[1000];
  __shared__ __align__(16) float gq[256];
  __shared__ float qmk[64];
  __shared__ float red4[4];

  gq[tid] = queryp[(size_t)(b * 8 + (tid >> 5)) * 256 + h * 32 + (tid & 31)];
  __syncthreads();
  if (tid < 64) {
    int v = tid >> 3, f = tid & 7;
    float a = 0.f;
    for (int k = 0; k < 32; k++)
      a += gq[v * 32 + k] * mw[(256 + h * 32 + k) * 8 + f];
    qmk[tid] = a;
  }
  __syncthreads();

  float tsum = 0.f;
  for (int e = tid; e < 1000; e += 256) {
    int v = e / 125;
    int n = n0 + (e - v * 125);
    const float4* nd4 = (const float4*)(node_dyn + ((size_t)(b*8+v)*1000 + n) * 8);
    float4 ndA = nd4[0], ndB = nd4[1];
    const float4* gk4 = (const float4*)(gKs + ((size_t)hb * 1000 + n) * 32);
    const float4* gq4 = (const float4*)(gq + v * 32);
    float s = 0.f;
    #pragma unroll
    for (int k4 = 0; k4 < 8; k4++) {
      float4 g = gk4[k4], q = gq4[k4];
      s += g.x*q.x + g.y*q.y + g.z*q.z + g.w*q.w;
    }
    const float* qm = qmk + v * 8;
    float dyn = ndA.x*qm[0] + ndA.y*qm[1] + ndA.z*qm[2] + ndA.w*qm[3]
              + ndB.x*qm[4] + ndB.y*qm[5] + ndB.z*qm[6] + ndB.w*qm[7];
    float cc = (s + dyn) * 0.17677669529663687f + logmask[(b*8+v)*1000 + n];
    float pv = __expf(cc);
    p[e] = pv;
    tsum += pv;
  }
  tsum = waveSum(tsum);
  if ((tid & 63) == 0) red4[tid >> 6] = tsum;
  __syncthreads();
  if (tid == 0) atomicAdd(csum + hb, red4[0]+red4[1]+red4[2]+red4[3]);
  // hstat[hb][v][k]
  {
    int v = tid >> 5, k = tid & 31;
    const float* gv = gVs + ((size_t)hb * 1000 + n0) * 32 + k;
    const float* pr = p + v * 125;
    float a = 0.f;
    #pragma unroll 5
    for (int i = 0; i < 125; i++) a += pr[i] * gv[(size_t)i * 32];
    atomicAdd(hstat + hb * 256 + tid, a);
  }
  // s8[hb][v][f]
  if (tid < 64) {
    int v = tid >> 3, f = tid & 7;
    const float* nd = node_dyn + ((size_t)(b*8+v)*1000 + n0) * 8 + f;
    const float* pr = p + v * 125;
    float a = 0.f;
    #pragma unroll 5
    for (int i = 0; i < 125; i++) a += pr[i] * nd[i * 8];
    atomicAdd(s8 + hb * 64 + tid, a);
  }
}

// K_fq: 64 blocks (one per bv): conc assembly + final_Q + lqM
__global__ __launch_bounds__(256) void k_fq(
    const float* __restrict__ po, float* __restrict__ W)
{
  int bv = blockIdx.x; int b = bv >> 3, v = bv & 7;
  int tid = threadIdx.x;
  const float* mw    = W + OFF_MW;
  const float* csum  = W + OFF_CSUM;
  const float* hstat = W + OFF_HSTAT;
  const float* s8    = W + OFF_S8;
  float* fqp = W + OFF_FQ;
  float* lqm = W + OFF_LQM;

  __shared__ __align__(16) float cl[256];
  __shared__ float fql[256];
  __shared__ float part[256];
  {
    int h = tid >> 5, k = tid & 31, hb = h * 8 + b;
    float dyn = 0.f;
    const float* s8p = s8 + hb * 64 + v * 8;
    const float* mwp = mw + (h * 32 + k) * 8;
    #pragma unroll
    for (int f = 0; f < 8; f++) dyn += s8p[f] * mwp[f];
    cl[tid] = (hstat[hb * 256 + v * 32 + k] + dyn) / csum[hb];
  }
  __syncthreads();
  float a = 0.f;
  const float4* c4 = (const float4*)cl;
  const float4* w4 = (const float4*)(po + (size_t)tid * 256);
  #pragma unroll 4
  for (int e = 0; e < 64; e++) {
    float4 cv = c4[e], wv = w4[e];
    a += cv.x*wv.x + cv.y*wv.y + cv.z*wv.z + cv.w*wv.w;
  }
  fql[tid] = a;
  fqp[(size_t)bv * 256 + tid] = a;
  __syncthreads();
  {
    int cc = tid >> 3, f = tid & 7;
    float s = 0.f;
    for (int d = cc * 8; d < cc * 8 + 8; d++) s += fql[d] * mw[(512 + d) * 8 + f];
    part[tid] = s;
  }
  __syncthreads();
  if (tid < 8) {
    float s = 0.f;
    for (int cc = 0; cc < 32; cc++) s += part[cc * 8 + tid];
    lqm[bv * 8 + tid] = s;
  }
}

// K_logits: 256 blocks = (b, slice of 32 nodes). Per-b expsum + packed argmax
// atomics; ticket last-block computes the 25 outputs (no extra launch).
__global__ __launch_bounds__(256) void k_logits(
    const float* __restrict__ lKs, const float* __restrict__ node_dyn,
    float* __restrict__ W, float* __restrict__ out)
{
  int blk = blockIdx.x, tid = threadIdx.x;
  int b = blk >> 5, slice = blk & 31;
  int nn = tid >> 3, v = tid & 7;
  int n = slice * 32 + nn;
  bool valid = (n < 1000);
  int n_c = valid ? n : 999;
  const float* fqp     = W + OFF_FQ;
  const float* lqm     = W + OFF_LQM;
  const float* logmask = W + OFF_LOGMASK;
  unsigned long long* packed = (unsigned long long*)(W + OFF_PACKED);
  float* expsum = W + OFF_EXPSUM;
  unsigned* done = (unsigned*)(W + OFF_DONE);

  __shared__ float red4[4];
  __shared__ unsigned long long rP[4];
  __shared__ unsigned ticket;

  const float4* A  = (const float4*)(fqp + (size_t)(b * 8 + v) * 256);
  const float4* Bk = (const float4*)(lKs + ((size_t)(b * 1000 + n_c)) * 256);
  float s = 0.f;
  #pragma unroll 8
  for (int d4 = 0; d4 < 64; d4++) {
    float4 x = A[d4], y = Bk[d4];
    s += x.x*y.x + x.y*y.y + x.z*y.z + x.w*y.w;
  }
  const float4* nd4 = (const float4*)(node_dyn + ((size_t)((b*8+v)*1000 + n_c)) * 8);
  float4 na = nd4[0], nb = nd4[1];
  const float* qm = lqm + (b * 8 + v) * 8;
  float dyn = na.x*qm[0] + na.y*qm[1] + na.z*qm[2] + na.w*qm[3]
            + nb.x*qm[4] + nb.y*qm[5] + nb.z*qm[6] + nb.w*qm[7];
  float z = (s + dyn) * 0.0625f;
  float L = tanhf(z) * 10.0f + logmask[(b * 8 + v) * 1000 + n_c];
  if (!valid) L = -INFINITY;
  float ex = __expf(L);                       // exp(-inf)=0
  unsigned idx = (unsigned)(v * 1000 + n_c);
  unsigned long long pk = ((unsigned long long)encF(L) << 32) | (unsigned)(~idx);
  float sEx = waveSum(ex);
  unsigned long long mP = waveMaxU(pk);
  if ((tid & 63) == 0) { red4[tid >> 6] = sEx; rP[tid >> 6] = mP; }
  __syncthreads();
  if (tid == 0) {
    float S = red4[0] + red4[1] + red4[2] + red4[3];
    unsigned long long P = rP[0];
    #pragma unroll
    for (int i = 1; i < 4; i++) P = (rP[i] > P) ? rP[i] : P;
    atomicAdd(expsum + b, S);
    atomicMax(packed + b, P);
    __threadfence();                          // release our contributions
    ticket = atomicAdd(done, 1u);
  }
  __syncthreads();
  if (ticket == 255) {                        // last block: all atomics done
    __threadfence();                          // acquire
    if (tid < 64) {
      float c = 0.f;
      if (tid < 8) {
        // coherent read-back via atomics (cross-XCD safe)
        unsigned long long pkv = atomicAdd(packed + tid, 0ull);
        float S = atomicAdd(expsum + tid, 0.0f);
        float best = decF((unsigned)(pkv >> 32));
        unsigned bi = ~(unsigned)(pkv & 0xffffffffu);
        float logprob = best - logf(S);
        float prob = __expf(logprob);
        out[tid]      = (float)(bi / 1000);
        out[8 + tid]  = (float)(bi % 1000);
        out[16 + tid] = logprob;
        c = prob * logprob;
      }
      c = waveSum(c);
      if (tid == 0) out[24] = -c;
    }
  }
}

extern "C" void kernel_launch(void* const* d_in, const int* in_sizes, int n_in,
                              void* d_out, int out_size, void* d_ws, size_t ws_size,
                              hipStream_t stream) {
  const float* fixedc   = (const float*)d_in[1];
  const float* prev     = (const float*)d_in[2];
  const float* node_dyn = (const float*)d_in[3];
  const float* veh      = (const float*)d_in[4];
  const float* gVs      = (const float*)d_in[5];
  const float* gKs      = (const float*)d_in[6];
  const float* lKs      = (const float*)d_in[7];
  const void*  mask     = d_in[8];
  const float* pcs      = (const float*)d_in[9];
  const float* pns1     = (const float*)d_in[10];
  const float* pns2     = (const float*)d_in[11];
  const float* po       = (const float*)d_in[12];
  float* W   = (float*)d_ws;
  float* out = (float*)d_out;

  k_prep<<<1082, 256, 0, stream>>>(pns1, pns2, prev, veh, fixedc, pcs, mask, W);
  k_attn<<<512, 256, 0, stream>>>(node_dyn, gVs, gKs, W);
  k_fq<<<64, 256, 0, stream>>>(po, W);
  k_logits<<<256, 256, 0, stream>>>(lKs, node_dyn, W, out);
}